// Round 17
// baseline (367.255 us; speedup 1.0000x reference)
//
#include <hip/hip_runtime.h>

// ---------------------------------------------------------------------------
// EnhancedBitcoinGCN: 3x GCNConv + LN/residual + (trivial) MHA + MLP head
// Round 16 -> 17:
//  * k_gemm_in1 phase 2 waited vmcnt(0) per K-step (4 exposed L2 round
//    trips/wave). Now software-pipelined: B1[0] issued after the h-stores;
//    each step issues B1[ks+1] then waits vmcnt(8) -> in-order retirement
//    drains {stores?, B1[ks]} whether or not the conditional stores issued
//    (they precede B1[0] in the queue) -> robust + 1 exposed latency.
//  * launch_bounds(256,6) on the fused kernel (VGPR<=85; r16 used 64) so
//    the 6-blocks/CU LDS occupancy is reachable by the allocator.
//  * Everything else unchanged from r16 (206.7us, absmax 0.03125).
// ---------------------------------------------------------------------------

typedef __attribute__((ext_vector_type(8))) _Float16 f16x8;
typedef __attribute__((ext_vector_type(4))) _Float16 f16x4;
typedef __attribute__((ext_vector_type(4))) float f32x4;

template <int V> struct IC { static constexpr int value = V; };

#define GLOAD_LDS16(gp, lp)                                        \
  __builtin_amdgcn_global_load_lds(                                \
      (const __attribute__((address_space(1))) void*)(gp),         \
      (__attribute__((address_space(3))) void*)(lp), 16, 0, 0)

template <int NV>
static __device__ __forceinline__ void wait_vm() {
  asm volatile("s_waitcnt vmcnt(%0)" :: "n"(NV) : "memory");
}
static __device__ __forceinline__ void wait_lgkm0() {
  asm volatile("s_waitcnt lgkmcnt(0)" ::: "memory");
  __builtin_amdgcn_sched_barrier(0);
}

// swizzled element index within a 16-row x NC-col f16 repack tile
static __device__ __forceinline__ int swz(int row, int col) {
  return row * 128 + (col ^ ((row & 7) << 3));   // NC=128 tiles
}
template <int NC>
static __device__ __forceinline__ int swzN(int row, int col) {
  return row * NC + (col ^ (((row & 7) << 3) & (NC - 1)));
}

// ---------------- CSR build ----------------
__global__ void k_count(const int* __restrict__ dst, int* __restrict__ counts, int e) {
  int i = blockIdx.x * blockDim.x + threadIdx.x;
  if (i < e) atomicAdd(&counts[dst[i]], 1);
}

__global__ __launch_bounds__(256) void k_scan_part(
    const int* __restrict__ counts, int* __restrict__ bsums, int n) {
  int tid = threadIdx.x;
  int i0 = blockIdx.x * 1024 + tid * 4;
  int s = 0;
#pragma unroll
  for (int k = 0; k < 4; k++) { int i = i0 + k; if (i < n) s += counts[i]; }
#pragma unroll
  for (int d = 1; d < 64; d <<= 1) s += __shfl_xor(s, d);
  __shared__ int wsum[4];
  int lane = tid & 63, w = tid >> 6;
  if (lane == 0) wsum[w] = s;
  __syncthreads();
  if (tid == 0) bsums[blockIdx.x] = wsum[0] + wsum[1] + wsum[2] + wsum[3];
}

__global__ __launch_bounds__(256) void k_scan_down(
    int* __restrict__ counts, const int* __restrict__ bsums,
    int* __restrict__ offsets, float* __restrict__ dinv, int n, int e, int nb) {
  int tid = threadIdx.x;
  int lane = tid & 63, w = tid >> 6;
  __shared__ int wsum[4], psum[4];
  int pv = (tid < nb && tid < blockIdx.x) ? bsums[tid] : 0;
#pragma unroll
  for (int d = 1; d < 64; d <<= 1) pv += __shfl_xor(pv, d);
  if (lane == 0) psum[w] = pv;
  __syncthreads();
  int blockpref = psum[0] + psum[1] + psum[2] + psum[3];

  int i0 = blockIdx.x * 1024 + tid * 4;
  int c[4]; int tsum = 0;
#pragma unroll
  for (int k = 0; k < 4; k++) { int i = i0 + k; c[k] = (i < n) ? counts[i] : 0; tsum += c[k]; }
  int v = tsum;
#pragma unroll
  for (int d = 1; d < 64; d <<= 1) { int t = __shfl_up(v, d); if (lane >= d) v += t; }
  if (lane == 63) wsum[w] = v;
  __syncthreads();
  int wadd = 0;
#pragma unroll
  for (int q = 0; q < 4; q++) if (q < w) wadd += wsum[q];
  int run = (v - tsum) + wadd + blockpref;
#pragma unroll
  for (int k = 0; k < 4; k++) {
    int i = i0 + k;
    if (i < n) {
      offsets[i] = run;
      dinv[i] = rsqrtf((float)(c[k] + 1));
      counts[i] = 0;
    }
    run += c[k];
  }
  if (blockIdx.x == 0 && tid == 0) offsets[n] = e;
}

__global__ void k_fill(const int* __restrict__ src, const int* __restrict__ dst,
                       const int* __restrict__ offsets, int* __restrict__ cursor,
                       const float* __restrict__ dinv, int2* __restrict__ csr, int e) {
  int i = blockIdx.x * blockDim.x + threadIdx.x;
  if (i >= e) return;
  int s = src[i], d = dst[i];
  int pos = atomicAdd(&cursor[d], 1);
  csr[offsets[d] + pos] = make_int2(s, __float_as_int(dinv[s] * dinv[d]));
}

// ---------------- weight prepack (fragment-ordered fp16, hi only) ----------
__device__ __forceinline__ void pack_hi(const float* __restrict__ W,
                                        _Float16* __restrict__ dst,
                                        int K, int N, int u) {
  int lane = u & 63; int rest = u >> 6; int CT = N >> 4;
  int ct = rest % CT, ks = rest / CT;
  int gcol = ct * 16 + (lane & 15);
  int gk0 = ks * 32 + (lane >> 4) * 8;
  size_t o = (size_t)(ks * CT + ct) * 512 + lane * 8;
#pragma unroll
  for (int i = 0; i < 8; i++) {
    float v = (gk0 + i < K) ? W[(size_t)(gk0 + i) * N + gcol] : 0.0f;
    dst[o + i] = (_Float16)v;
  }
}

__global__ void k_setup(const float* __restrict__ Wi, const float* __restrict__ Wg1,
                        const float* __restrict__ Wg2, const float* __restrict__ Wg3,
                        _Float16* __restrict__ pWi, _Float16* __restrict__ pWg1,
                        _Float16* __restrict__ pWg2, _Float16* __restrict__ pWg3,
                        int* __restrict__ counts, float* __restrict__ zp, int n) {
  int b = blockIdx.x;
  if (b < 25) {
    int t = b * 256 + threadIdx.x;
    if (t < 3072) pack_hi(Wi, pWi, 164, 128, t);
    else if (t < 5120) pack_hi(Wg1, pWg1, 128, 128, t - 3072);
    else if (t < 6144) pack_hi(Wg2, pWg2, 128, 64, t - 5120);
    else if (t < 6400) pack_hi(Wg3, pWg3, 64, 32, t - 6144);
  } else {
    if (b == 25 && threadIdx.x < 64) zp[threadIdx.x] = 0.0f;
    int i = (b - 25) * 256 + threadIdx.x;
    if (i < n) counts[i] = 0;
  }
}

// ---------------- fused input GEMM + conv1 GEMM (64 rows, 4 waves) ---------
__global__ __launch_bounds__(256, 6) void k_gemm_in1(
    const float* __restrict__ x, const _Float16* __restrict__ pB,
    const _Float16* __restrict__ pB1, const float* __restrict__ bias,
    const float* __restrict__ gamma, const float* __restrict__ beta,
    const float* __restrict__ zp, _Float16* __restrict__ outH,
    _Float16* __restrict__ outXW, int n) {
  constexpr int N = 128, CT = 8;
  __shared__ __align__(16) float sAi[4][3][512];  // 4 waves x 3 ring x 2KB
  int tid = threadIdx.x;
  int lane = tid & 63, w = tid >> 6;
  int rowbase = blockIdx.x * 64 + w * 16;
  const f16x8* Bf = (const f16x8*)pB;
  const f16x8* Bf1 = (const f16x8*)pB1;

  auto stage = [&](int ks, int buf) {
#pragma unroll
    for (int j = 0; j < 2; j++) {
      int r_ = j * 8 + (lane >> 3);
      int c_ = (lane & 7) ^ (lane >> 3);
      int rg = rowbase + r_;
      bool ok = (rg < n) && (ks < 5 || c_ == 0);
      const void* s = ok ? (const void*)(x + (size_t)rg * 164 + ks * 32 + c_ * 4)
                         : (const void*)zp;
      GLOAD_LDS16(s, &sAi[w][buf][j * 256]);
    }
  };

  f32x4 acc[CT];
#pragma unroll
  for (int c = 0; c < CT; c++) acc[c] = (f32x4)0.0f;

  int rr = lane & 15;
  int c0 = (lane >> 4) * 2;
  int s0 = c0 ^ (rr & 7);
  int s1 = (c0 + 1) ^ (rr & 7);

  f16x8 bfr[2][CT];
  stage(0, 0);
  stage(1, 1);
#pragma unroll
  for (int c = 0; c < CT; c++) bfr[0][c] = Bf[c * 64 + lane];

  auto step = [&](auto ksc, auto wnc) {
    constexpr int ks = decltype(ksc)::value;
    constexpr int WN = decltype(wnc)::value;
    if constexpr (ks + 1 < 6) {
#pragma unroll
      for (int c = 0; c < CT; c++)
        bfr[(ks + 1) & 1][c] = Bf[((ks + 1) * CT + c) * 64 + lane];
    }
    if constexpr (ks + 2 < 6) stage(ks + 2, (ks + 2) % 3);
    wait_vm<WN>();
    const float* bp = &sAi[w][ks % 3][0];
    float4 u0 = *(const float4*)&bp[rr * 32 + s0 * 4];
    float4 u1 = *(const float4*)&bp[rr * 32 + s1 * 4];
    float v[8] = {u0.x, u0.y, u0.z, u0.w, u1.x, u1.y, u1.z, u1.w};
    f16x8 ah;
#pragma unroll
    for (int i = 0; i < 8; i++) ah[i] = (_Float16)v[i];
#pragma unroll
    for (int c = 0; c < CT; c++)
      acc[c] = __builtin_amdgcn_mfma_f32_16x16x32_f16(ah, bfr[ks & 1][c], acc[c], 0, 0, 0);
  };
  step(IC<0>{}, IC<10>{});
  step(IC<1>{}, IC<12>{});
  step(IC<2>{}, IC<12>{});
  step(IC<3>{}, IC<12>{});
  step(IC<4>{}, IC<10>{});
  step(IC<5>{}, IC<0>{});

  // bias + relu + LN (row lives in a 16-lane group; wave-local)
  int r0 = (lane >> 4) * 4;
  int li = lane & 15;
  float s1v[4] = {0, 0, 0, 0}, s2v[4] = {0, 0, 0, 0};
#pragma unroll
  for (int c = 0; c < CT; c++) {
    float bb = bias[c * 16 + li];
#pragma unroll
    for (int r = 0; r < 4; r++) {
      float t = acc[c][r] + bb;
      t = t > 0.0f ? t : 0.0f;
      acc[c][r] = t;
      s1v[r] += t;
      s2v[r] += t * t;
    }
  }
#pragma unroll
  for (int m = 1; m < 16; m <<= 1) {
#pragma unroll
    for (int r = 0; r < 4; r++) {
      s1v[r] += __shfl_xor(s1v[r], m);
      s2v[r] += __shfl_xor(s2v[r], m);
    }
  }
  // repack h into wave LDS (swizzled 16x128 f16 = 4KB), store coalesced
  wait_lgkm0();
  _Float16* lr = (_Float16*)&sAi[w][0][0];
#pragma unroll
  for (int c = 0; c < CT; c++) {
    float gv = gamma[c * 16 + li], bv = beta[c * 16 + li];
#pragma unroll
    for (int r = 0; r < 4; r++) {
      float mean = s1v[r] * (1.0f / N);
      float var = s2v[r] * (1.0f / N) - mean * mean;
      float rs = rsqrtf(var + 1e-5f);
      lr[swz(r0 + r, c * 16 + li)] =
          (_Float16)((acc[c][r] - mean) * rs * gv + bv);
    }
  }
  wait_lgkm0();
#pragma unroll
  for (int i = 0; i < 4; i++) {
    int chunk = i * 64 + lane;
    int rloc = chunk >> 4;
    int cc = chunk & 15;
    if (rowbase + rloc < n)
      *(f16x8*)&outH[(size_t)(rowbase + rloc) * 128 + cc * 8] =
          *(const f16x8*)&lr[swz(rloc, cc * 8)];
  }

  // ---- phase 2: xw1 = h @ Wg1 (A from swizzled LDS; B software-pipelined)
  // Queue: [h-stores(<=4)] B1[0] | per-step: issue B1[ks+1], wait vmcnt(8)
  // -> retires everything older than B1[ks+1] (stores + B1[ks]) whether or
  // not the conditional stores issued. One exposed L2 latency total.
  int kof = (lane >> 4) * 8;
  f16x8 b1a[CT], b1b[CT];
#pragma unroll
  for (int c = 0; c < CT; c++) b1a[c] = Bf1[c * 64 + lane];  // B1[0]
#pragma unroll
  for (int c = 0; c < CT; c++) acc[c] = (f32x4)0.0f;

  // ks = 0
#pragma unroll
  for (int c = 0; c < CT; c++) b1b[c] = Bf1[(1 * CT + c) * 64 + lane];  // B1[1]
  wait_vm<8>();
  {
    f16x8 av = *(const f16x8*)&lr[swz(rr, 0 * 32 + kof)];
#pragma unroll
    for (int c = 0; c < CT; c++)
      acc[c] = __builtin_amdgcn_mfma_f32_16x16x32_f16(av, b1a[c], acc[c], 0, 0, 0);
  }
  // ks = 1
#pragma unroll
  for (int c = 0; c < CT; c++) b1a[c] = Bf1[(2 * CT + c) * 64 + lane];  // B1[2]
  wait_vm<8>();
  {
    f16x8 av = *(const f16x8*)&lr[swz(rr, 1 * 32 + kof)];
#pragma unroll
    for (int c = 0; c < CT; c++)
      acc[c] = __builtin_amdgcn_mfma_f32_16x16x32_f16(av, b1b[c], acc[c], 0, 0, 0);
  }
  // ks = 2
#pragma unroll
  for (int c = 0; c < CT; c++) b1b[c] = Bf1[(3 * CT + c) * 64 + lane];  // B1[3]
  wait_vm<8>();
  {
    f16x8 av = *(const f16x8*)&lr[swz(rr, 2 * 32 + kof)];
#pragma unroll
    for (int c = 0; c < CT; c++)
      acc[c] = __builtin_amdgcn_mfma_f32_16x16x32_f16(av, b1a[c], acc[c], 0, 0, 0);
  }
  // ks = 3
  wait_vm<0>();
  {
    f16x8 av = *(const f16x8*)&lr[swz(rr, 3 * 32 + kof)];
#pragma unroll
    for (int c = 0; c < CT; c++)
      acc[c] = __builtin_amdgcn_mfma_f32_16x16x32_f16(av, b1b[c], acc[c], 0, 0, 0);
  }

  // repack xw1 + coalesced store
  wait_lgkm0();
#pragma unroll
  for (int c = 0; c < CT; c++) {
#pragma unroll
    for (int r = 0; r < 4; r++)
      lr[swz(r0 + r, c * 16 + li)] = (_Float16)acc[c][r];
  }
  wait_lgkm0();
#pragma unroll
  for (int i = 0; i < 4; i++) {
    int chunk = i * 64 + lane;
    int rloc = chunk >> 4;
    int cc = chunk & 15;
    if (rowbase + rloc < n)
      *(f16x8*)&outXW[(size_t)(rowbase + rloc) * 128 + cc * 8] =
          *(const f16x8*)&lr[swz(rloc, cc * 8)];
  }
}

// ---------------- conv GEMM: xw = A@W (64 rows, 4 waves) -------------------
template <int K, int N>
__global__ __launch_bounds__(256, 4) void k_gemm_f16(
    const _Float16* __restrict__ A, const _Float16* __restrict__ pB,
    const float* __restrict__ zp, _Float16* __restrict__ out, int n) {
  constexpr int KS = K / 32, CT = N / 16;
  __shared__ __align__(16) _Float16 sB[KS * CT * 512];
  __shared__ __align__(16) _Float16 sA[4][KS][512];
  int tid = threadIdx.x;
  int lane = tid & 63, w = tid >> 6;
  int rowbase = blockIdx.x * 64 + w * 16;

  for (int u = w; u < KS * CT; u += 4)
    GLOAD_LDS16(pB + (size_t)u * 512 + lane * 8, &sB[(size_t)u * 512]);

  int r_ = lane >> 2;
  int c_ = (lane & 3) ^ ((r_ >> 1) & 3);
  int rg = rowbase + r_;
  bool rok = rg < n;
  for (int ks = 0; ks < KS; ks++) {
    const void* s = rok ? (const void*)(A + (size_t)rg * K + ks * 32 + c_ * 8)
                        : (const void*)zp;
    GLOAD_LDS16(s, &sA[w][ks][0]);
  }
  wait_vm<KS>();
  __builtin_amdgcn_s_barrier();

  f32x4 acc[CT];
#pragma unroll
  for (int c = 0; c < CT; c++) acc[c] = (f32x4)0.0f;

  int rr = lane & 15;
  int slot = (lane >> 4) ^ ((rr >> 1) & 3);

  auto cstep = [&](auto ksc) {
    constexpr int ks = decltype(ksc)::value;
    wait_vm<KS - 1 - ks>();
    f16x8 av = *(const f16x8*)&sA[w][ks][rr * 32 + slot * 8];
#pragma unroll
    for (int c = 0; c < CT; c++) {
      f16x8 b = *(const f16x8*)&sB[(size_t)(ks * CT + c) * 512 + lane * 8];
      acc[c] = __builtin_amdgcn_mfma_f32_16x16x32_f16(av, b, acc[c], 0, 0, 0);
    }
  };
  cstep(IC<0>{});
  if constexpr (KS > 1) cstep(IC<1>{});
  if constexpr (KS > 2) cstep(IC<2>{});
  if constexpr (KS > 3) cstep(IC<3>{});

  int r0 = (lane >> 4) * 4;
  int li = lane & 15;
  wait_lgkm0();
  _Float16* lr = &sA[w][0][0];
#pragma unroll
  for (int c = 0; c < CT; c++) {
#pragma unroll
    for (int r = 0; r < 4; r++)
      lr[swzN<N>(r0 + r, c * 16 + li)] = (_Float16)acc[c][r];
  }
  wait_lgkm0();
#pragma unroll
  for (int i = 0; i < N / 32; i++) {
    int chunk = i * 64 + lane;
    int rloc = chunk / (N / 8);
    int cc = chunk % (N / 8);
    if (rowbase + rloc < n)
      *(f16x8*)&out[(size_t)(rowbase + rloc) * N + cc * 8] =
          *(const f16x8*)&lr[swzN<N>(rloc, cc * 8)];
  }
}

// ---------------- gather, 8 cols/thread (f16x8), 8-deep batches ------------
template <int OUT_D, int MODE>
__global__ __launch_bounds__(256, 4) void k_gather8(
    const int* __restrict__ off, const int2* __restrict__ csr,
    const _Float16* __restrict__ xw, const float* __restrict__ dinv,
    const float* __restrict__ bias, const _Float16* __restrict__ auxh,
    const float* __restrict__ gamma, const float* __restrict__ beta,
    _Float16* __restrict__ out, int n) {
  constexpr int TPN = OUT_D / 8;
  constexpr int NPB = 256 / TPN;
  int tid = threadIdx.x;
  int node = blockIdx.x * NPB + tid / TPN;
  int li = tid % TPN;
  if (node >= n) return;
  int start = off[node], end = off[node + 1];
  float di = dinv[node];
  float d2 = di * di;
  const _Float16* xp = xw + 8 * li;
  f16x8 self = *(const f16x8*)(xp + (size_t)node * OUT_D);
  f16x8 hres;
  if constexpr (MODE == 0)
    hres = *(const f16x8*)(auxh + (size_t)node * OUT_D + 8 * li);
  float a[8];
#pragma unroll
  for (int q = 0; q < 8; q++) a[q] = (float)self[q] * d2 + bias[8 * li + q];
  for (int cb = start; cb < end; cb += TPN) {
    int m = end - cb; if (m > TPN) m = TPN;
    int sv = node; float nv = 0.0f;
    if (li < m) { int2 me = csr[cb + li]; sv = me.x; nv = __int_as_float(me.y); }
    for (int j0 = 0; j0 < m; j0 += 8) {
      int s[8]; float wv[8];
#pragma unroll
      for (int q = 0; q < 8; q++) {
        s[q] = __shfl(sv, j0 + q, TPN);
        wv[q] = __shfl(nv, j0 + q, TPN);
      }
      f16x8 v[8];
#pragma unroll
      for (int q = 0; q < 8; q++) v[q] = *(const f16x8*)(xp + (size_t)s[q] * OUT_D);
#pragma unroll
      for (int q = 0; q < 8; q++) {
#pragma unroll
        for (int c = 0; c < 8; c++) a[c] += (float)v[q][c] * wv[q];
      }
    }
  }
  _Float16* po = out + (size_t)node * OUT_D + 8 * li;
  if constexpr (MODE == 0) {
    f16x8 o;
#pragma unroll
    for (int q = 0; q < 8; q++)
      o[q] = (_Float16)((a[q] > 0.0f ? a[q] : 0.0f) + (float)hres[q]);
    *(f16x8*)po = o;
  } else {
    float s1 = 0.0f, s2 = 0.0f;
#pragma unroll
    for (int q = 0; q < 8; q++) {
      a[q] = a[q] > 0.0f ? a[q] : 0.0f;
      s1 += a[q];
      s2 += a[q] * a[q];
    }
#pragma unroll
    for (int d = 1; d < TPN; d <<= 1) {
      s1 += __shfl_xor(s1, d, TPN);
      s2 += __shfl_xor(s2, d, TPN);
    }
    float m_ = s1 * (1.0f / OUT_D);
    float var = s2 * (1.0f / OUT_D) - m_ * m_;
    float rs = rsqrtf(var + 1e-5f);
    f16x8 o;
#pragma unroll
    for (int q = 0; q < 8; q++)
      o[q] = (_Float16)((a[q] - m_) * rs * gamma[8 * li + q] + beta[8 * li + q]);
    *(f16x8*)po = o;
  }
}

// ---------------- conv3 gather, 4 cols/thread (TPN=8) ----------------------
__global__ __launch_bounds__(256, 4) void k_gather3(
    const int* __restrict__ off, const int2* __restrict__ csr,
    const _Float16* __restrict__ xw, const float* __restrict__ dinv,
    const float* __restrict__ bias, _Float16* __restrict__ out, int n) {
  constexpr int OUT_D = 32, TPN = 8, NPB = 32;
  int tid = threadIdx.x;
  int node = blockIdx.x * NPB + tid / TPN;
  int li = tid % TPN;
  if (node >= n) return;
  int start = off[node], end = off[node + 1];
  float di = dinv[node];
  float d2 = di * di;
  const _Float16* xp = xw + 4 * li;
  f16x4 self = *(const f16x4*)(xp + (size_t)node * OUT_D);
  float a0 = (float)self[0] * d2 + bias[4 * li + 0];
  float a1 = (float)self[1] * d2 + bias[4 * li + 1];
  float a2 = (float)self[2] * d2 + bias[4 * li + 2];
  float a3 = (float)self[3] * d2 + bias[4 * li + 3];
  for (int cb = start; cb < end; cb += TPN) {
    int m = end - cb; if (m > TPN) m = TPN;
    int sv = node; float nv = 0.0f;
    if (li < m) { int2 me = csr[cb + li]; sv = me.x; nv = __int_as_float(me.y); }
    for (int j0 = 0; j0 < m; j0 += 8) {
      int s[8]; float wv[8];
#pragma unroll
      for (int q = 0; q < 8; q++) {
        s[q] = __shfl(sv, j0 + q, TPN);
        wv[q] = __shfl(nv, j0 + q, TPN);
      }
      f16x4 v[8];
#pragma unroll
      for (int q = 0; q < 8; q++) v[q] = *(const f16x4*)(xp + (size_t)s[q] * OUT_D);
#pragma unroll
      for (int q = 0; q < 8; q++) {
        a0 += (float)v[q][0] * wv[q];
        a1 += (float)v[q][1] * wv[q];
        a2 += (float)v[q][2] * wv[q];
        a3 += (float)v[q][3] * wv[q];
      }
    }
  }
  f16x4 o;
  o[0] = (_Float16)a0; o[1] = (_Float16)a1;
  o[2] = (_Float16)a2; o[3] = (_Float16)a3;
  *(f16x4*)(out + (size_t)node * OUT_D + 4 * li) = o;
}

// ---------------- tail: relu(agg3) -> Wv -> Wo -> Wc1 -> Wc2 -> Wc3 --------
__global__ __launch_bounds__(256) void k_tail(
    const _Float16* __restrict__ agg3, const float* __restrict__ Wv,
    const float* __restrict__ bv, const float* __restrict__ Wo,
    const float* __restrict__ bo, const float* __restrict__ Wc1,
    const float* __restrict__ bc1, const float* __restrict__ Wc2,
    const float* __restrict__ bc2, const float* __restrict__ Wc3,
    const float* __restrict__ bc3, float* __restrict__ out, int n) {
  __shared__ float sWv[1024], sWo[1024], sWc1[512], sWc2[512];
  __shared__ float sbv[32], sbo[32], sbc2[32], sWc3[32], sbc1[16], sbc3[1];
  int tid = threadIdx.x;
  for (int i = tid; i < 1024; i += 256) { sWv[i] = Wv[i]; sWo[i] = Wo[i]; }
  for (int i = tid; i < 512; i += 256) { sWc1[i] = Wc1[i]; sWc2[i] = Wc2[i]; }
  if (tid < 32) { sbv[tid] = bv[tid]; sbo[tid] = bo[tid];
                  sbc2[tid] = bc2[tid]; sWc3[tid] = Wc3[tid]; }
  if (tid < 16) sbc1[tid] = bc1[tid];
  if (tid == 0) sbc3[0] = bc3[0];
  __syncthreads();
  int node = blockIdx.x * blockDim.x + tid;
  if (node >= n) return;
  float a[32];
  const f16x8* row8 = (const f16x8*)(agg3 + (size_t)node * 32);
#pragma unroll
  for (int q = 0; q < 4; q++) {
    f16x8 t = row8[q];
#pragma unroll
    for (int i = 0; i < 8; i++) {
      float f = (float)t[i];
      a[8 * q + i] = f > 0.0f ? f : 0.0f;
    }
  }
  float v[32];
#pragma unroll
  for (int j = 0; j < 32; j++) v[j] = sbv[j];
  for (int k = 0; k < 32; k++) {
#pragma unroll
    for (int j = 0; j < 32; j++) v[j] += a[k] * sWv[k * 32 + j];
  }
  float o[32];
#pragma unroll
  for (int j = 0; j < 32; j++) o[j] = sbo[j];
  for (int k = 0; k < 32; k++) {
#pragma unroll
    for (int j = 0; j < 32; j++) o[j] += v[k] * sWo[k * 32 + j];
  }
  float c1[16];
#pragma unroll
  for (int j = 0; j < 16; j++) c1[j] = sbc1[j];
  for (int k = 0; k < 32; k++) {
#pragma unroll
    for (int j = 0; j < 16; j++) c1[j] += o[k] * sWc1[k * 16 + j];
  }
#pragma unroll
  for (int j = 0; j < 16; j++) c1[j] = c1[j] > 0.0f ? c1[j] : 0.0f;
  float c2[32];
#pragma unroll
  for (int j = 0; j < 32; j++) c2[j] = sbc2[j];
  for (int k = 0; k < 16; k++) {
#pragma unroll
    for (int j = 0; j < 32; j++) c2[j] += c1[k] * sWc2[k * 32 + j];
  }
  float r = sbc3[0];
#pragma unroll
  for (int k = 0; k < 32; k++) {
    float c = c2[k] > 0.0f ? c2[k] : 0.0f;
    r += c * sWc3[k];
  }
  out[node] = r;
}

// ---------------------------------------------------------------------------
extern "C" void kernel_launch(void* const* d_in, const int* in_sizes, int n_in,
                              void* d_out, int out_size, void* d_ws, size_t ws_size,
                              hipStream_t stream) {
  const float* x   = (const float*)d_in[0];
  const int* ei    = (const int*)d_in[1];
  const float* Wi  = (const float*)d_in[2];
  const float* bi  = (const float*)d_in[3];
  const float* g1  = (const float*)d_in[4];
  const float* b1  = (const float*)d_in[5];
  const float* Wg1 = (const float*)d_in[6];
  const float* bg1 = (const float*)d_in[7];
  const float* Wg2 = (const float*)d_in[8];
  const float* bg2 = (const float*)d_in[9];
  const float* g2  = (const float*)d_in[10];
  const float* b2  = (const float*)d_in[11];
  const float* Wg3 = (const float*)d_in[12];
  const float* bg3 = (const float*)d_in[13];
  // d_in[14..17]: Wq,bq,Wk,bk — mathematically dead (softmax over 1 key == 1)
  const float* Wv  = (const float*)d_in[18];
  const float* bv  = (const float*)d_in[19];
  const float* Wo  = (const float*)d_in[20];
  const float* bo  = (const float*)d_in[21];
  const float* Wc1 = (const float*)d_in[22];
  const float* bc1 = (const float*)d_in[23];
  const float* Wc2 = (const float*)d_in[24];
  const float* bc2 = (const float*)d_in[25];
  const float* Wc3 = (const float*)d_in[26];
  const float* bc3 = (const float*)d_in[27];

  const int n = in_sizes[0] / 164;
  const int e = in_sizes[1] / 2;
  const int* src = ei;
  const int* dst = ei + e;

  // workspace layout (256B aligned)
  char* ws = (char*)d_ws;
  size_t off = 0;
  auto alloc = [&](size_t bytes) {
    char* p = ws + off;
    off += (bytes + 255) & ~(size_t)255;
    return p;
  };
  _Float16* A     = (_Float16*)alloc((size_t)n * 128 * 2);
  _Float16* B     = (_Float16*)alloc((size_t)n * 128 * 2);
  _Float16* C     = (_Float16*)alloc((size_t)n * 128 * 2);
  float* dinv     = (float*)alloc((size_t)n * 4);
  int*   counts   = (int*)alloc((size_t)n * 4);
  int*   offsets  = (int*)alloc((size_t)(n + 1) * 4);
  int*   bsums    = (int*)alloc(256 * 4);
  int2*  csr      = (int2*)alloc((size_t)e * 8);
  _Float16* pWi   = (_Float16*)alloc(3072 * 16);
  _Float16* pWg1  = (_Float16*)alloc(2048 * 16);
  _Float16* pWg2  = (_Float16*)alloc(1024 * 16);
  _Float16* pWg3  = (_Float16*)alloc(256 * 16);
  float* zp       = (float*)alloc(64 * 4);
  (void)ws_size;

  const int BS = 256;
  const int SB = (n + 1023) / 1024;
  const int GB = (n + 63) / 64;   // 64-row gemm blocks (1563)

  // ---- setup ----
  k_setup<<<25 + (n + 255) / 256, 256, 0, stream>>>(
      Wi, Wg1, Wg2, Wg3, pWi, pWg1, pWg2, pWg3, counts, zp, n);

  // ---- CSR build ----
  k_count<<<(e + BS - 1) / BS, BS, 0, stream>>>(dst, counts, e);
  k_scan_part<<<SB, 256, 0, stream>>>(counts, bsums, n);
  k_scan_down<<<SB, 256, 0, stream>>>(counts, bsums, offsets, dinv, n, e, SB);
  k_fill<<<(e + BS - 1) / BS, BS, 0, stream>>>(src, dst, offsets, counts, dinv,
                                               csr, e);

  // ---- fused input + conv1 GEMM: A = h, B = xw1 ----
  k_gemm_in1<<<GB, 256, 0, stream>>>(x, pWi, pWg1, bi, g1, b1, zp, A, B, n);

  // ---- conv1 gather -> C = h1 = relu(agg)+h ----
  k_gather8<128, 0><<<(n + 15) / 16, 256, 0, stream>>>(
      offsets, csr, B, dinv, bg1, A, nullptr, nullptr, C, n);

  // ---- conv2 ----
  k_gemm_f16<128, 64><<<GB, 256, 0, stream>>>(C, pWg2, zp, A, n);
  k_gather8<64, 1><<<(n + 31) / 32, 256, 0, stream>>>(
      offsets, csr, A, dinv, bg2, nullptr, g2, b2, B, n);

  // ---- conv3 ----
  k_gemm_f16<64, 32><<<GB, 256, 0, stream>>>(B, pWg3, zp, A, n);
  k_gather3<<<(n + 31) / 32, 256, 0, stream>>>(
      offsets, csr, A, dinv, bg3, C, n);

  // ---- tail ----
  k_tail<<<(n + BS - 1) / BS, BS, 0, stream>>>(
      C, Wv, bv, Wo, bo, Wc1, bc1, Wc2, bc2, Wc3, bc3, (float*)d_out, n);
}

// Round 18
// 220.022 us; speedup vs baseline: 1.6692x; 1.6692x over previous
//
#include <hip/hip_runtime.h>

// ---------------------------------------------------------------------------
// EnhancedBitcoinGCN: 3x GCNConv + LN/residual + (trivial) MHA + MLP head
// Round 17 -> 18 (spill-revert):
//  * r17 regressed 207->367us: launch_bounds(256,6) cut the VGPR cap to ~85
//    while the new phase-2 B double-buffer needed ~105 -> allocator SPILLED
//    acc+B to scratch (VGPR 64->40, FETCH 38->228MB, WRITE 56->380MB).
//  * Fix: launch_bounds back to (256,4) (cap 128); KEEP the phase-2 B
//    software-pipeline (issue B1[ks+1], wait vmcnt(8): one exposed latency).
//  * Everything else identical to r16/r17.
// ---------------------------------------------------------------------------

typedef __attribute__((ext_vector_type(8))) _Float16 f16x8;
typedef __attribute__((ext_vector_type(4))) _Float16 f16x4;
typedef __attribute__((ext_vector_type(4))) float f32x4;

template <int V> struct IC { static constexpr int value = V; };

#define GLOAD_LDS16(gp, lp)                                        \
  __builtin_amdgcn_global_load_lds(                                \
      (const __attribute__((address_space(1))) void*)(gp),         \
      (__attribute__((address_space(3))) void*)(lp), 16, 0, 0)

template <int NV>
static __device__ __forceinline__ void wait_vm() {
  asm volatile("s_waitcnt vmcnt(%0)" :: "n"(NV) : "memory");
}
static __device__ __forceinline__ void wait_lgkm0() {
  asm volatile("s_waitcnt lgkmcnt(0)" ::: "memory");
  __builtin_amdgcn_sched_barrier(0);
}

// swizzled element index within a 16-row x NC-col f16 repack tile
static __device__ __forceinline__ int swz(int row, int col) {
  return row * 128 + (col ^ ((row & 7) << 3));   // NC=128 tiles
}
template <int NC>
static __device__ __forceinline__ int swzN(int row, int col) {
  return row * NC + (col ^ (((row & 7) << 3) & (NC - 1)));
}

// ---------------- CSR build ----------------
__global__ void k_count(const int* __restrict__ dst, int* __restrict__ counts, int e) {
  int i = blockIdx.x * blockDim.x + threadIdx.x;
  if (i < e) atomicAdd(&counts[dst[i]], 1);
}

__global__ __launch_bounds__(256) void k_scan_part(
    const int* __restrict__ counts, int* __restrict__ bsums, int n) {
  int tid = threadIdx.x;
  int i0 = blockIdx.x * 1024 + tid * 4;
  int s = 0;
#pragma unroll
  for (int k = 0; k < 4; k++) { int i = i0 + k; if (i < n) s += counts[i]; }
#pragma unroll
  for (int d = 1; d < 64; d <<= 1) s += __shfl_xor(s, d);
  __shared__ int wsum[4];
  int lane = tid & 63, w = tid >> 6;
  if (lane == 0) wsum[w] = s;
  __syncthreads();
  if (tid == 0) bsums[blockIdx.x] = wsum[0] + wsum[1] + wsum[2] + wsum[3];
}

__global__ __launch_bounds__(256) void k_scan_down(
    int* __restrict__ counts, const int* __restrict__ bsums,
    int* __restrict__ offsets, float* __restrict__ dinv, int n, int e, int nb) {
  int tid = threadIdx.x;
  int lane = tid & 63, w = tid >> 6;
  __shared__ int wsum[4], psum[4];
  int pv = (tid < nb && tid < blockIdx.x) ? bsums[tid] : 0;
#pragma unroll
  for (int d = 1; d < 64; d <<= 1) pv += __shfl_xor(pv, d);
  if (lane == 0) psum[w] = pv;
  __syncthreads();
  int blockpref = psum[0] + psum[1] + psum[2] + psum[3];

  int i0 = blockIdx.x * 1024 + tid * 4;
  int c[4]; int tsum = 0;
#pragma unroll
  for (int k = 0; k < 4; k++) { int i = i0 + k; c[k] = (i < n) ? counts[i] : 0; tsum += c[k]; }
  int v = tsum;
#pragma unroll
  for (int d = 1; d < 64; d <<= 1) { int t = __shfl_up(v, d); if (lane >= d) v += t; }
  if (lane == 63) wsum[w] = v;
  __syncthreads();
  int wadd = 0;
#pragma unroll
  for (int q = 0; q < 4; q++) if (q < w) wadd += wsum[q];
  int run = (v - tsum) + wadd + blockpref;
#pragma unroll
  for (int k = 0; k < 4; k++) {
    int i = i0 + k;
    if (i < n) {
      offsets[i] = run;
      dinv[i] = rsqrtf((float)(c[k] + 1));
      counts[i] = 0;
    }
    run += c[k];
  }
  if (blockIdx.x == 0 && tid == 0) offsets[n] = e;
}

__global__ void k_fill(const int* __restrict__ src, const int* __restrict__ dst,
                       const int* __restrict__ offsets, int* __restrict__ cursor,
                       const float* __restrict__ dinv, int2* __restrict__ csr, int e) {
  int i = blockIdx.x * blockDim.x + threadIdx.x;
  if (i >= e) return;
  int s = src[i], d = dst[i];
  int pos = atomicAdd(&cursor[d], 1);
  csr[offsets[d] + pos] = make_int2(s, __float_as_int(dinv[s] * dinv[d]));
}

// ---------------- weight prepack (fragment-ordered fp16, hi only) ----------
__device__ __forceinline__ void pack_hi(const float* __restrict__ W,
                                        _Float16* __restrict__ dst,
                                        int K, int N, int u) {
  int lane = u & 63; int rest = u >> 6; int CT = N >> 4;
  int ct = rest % CT, ks = rest / CT;
  int gcol = ct * 16 + (lane & 15);
  int gk0 = ks * 32 + (lane >> 4) * 8;
  size_t o = (size_t)(ks * CT + ct) * 512 + lane * 8;
#pragma unroll
  for (int i = 0; i < 8; i++) {
    float v = (gk0 + i < K) ? W[(size_t)(gk0 + i) * N + gcol] : 0.0f;
    dst[o + i] = (_Float16)v;
  }
}

__global__ void k_setup(const float* __restrict__ Wi, const float* __restrict__ Wg1,
                        const float* __restrict__ Wg2, const float* __restrict__ Wg3,
                        _Float16* __restrict__ pWi, _Float16* __restrict__ pWg1,
                        _Float16* __restrict__ pWg2, _Float16* __restrict__ pWg3,
                        int* __restrict__ counts, float* __restrict__ zp, int n) {
  int b = blockIdx.x;
  if (b < 25) {
    int t = b * 256 + threadIdx.x;
    if (t < 3072) pack_hi(Wi, pWi, 164, 128, t);
    else if (t < 5120) pack_hi(Wg1, pWg1, 128, 128, t - 3072);
    else if (t < 6144) pack_hi(Wg2, pWg2, 128, 64, t - 5120);
    else if (t < 6400) pack_hi(Wg3, pWg3, 64, 32, t - 6144);
  } else {
    if (b == 25 && threadIdx.x < 64) zp[threadIdx.x] = 0.0f;
    int i = (b - 25) * 256 + threadIdx.x;
    if (i < n) counts[i] = 0;
  }
}

// ---------------- fused input GEMM + conv1 GEMM (64 rows, 4 waves) ---------
__global__ __launch_bounds__(256, 4) void k_gemm_in1(
    const float* __restrict__ x, const _Float16* __restrict__ pB,
    const _Float16* __restrict__ pB1, const float* __restrict__ bias,
    const float* __restrict__ gamma, const float* __restrict__ beta,
    const float* __restrict__ zp, _Float16* __restrict__ outH,
    _Float16* __restrict__ outXW, int n) {
  constexpr int N = 128, CT = 8;
  __shared__ __align__(16) float sAi[4][3][512];  // 4 waves x 3 ring x 2KB
  int tid = threadIdx.x;
  int lane = tid & 63, w = tid >> 6;
  int rowbase = blockIdx.x * 64 + w * 16;
  const f16x8* Bf = (const f16x8*)pB;
  const f16x8* Bf1 = (const f16x8*)pB1;

  auto stage = [&](int ks, int buf) {
#pragma unroll
    for (int j = 0; j < 2; j++) {
      int r_ = j * 8 + (lane >> 3);
      int c_ = (lane & 7) ^ (lane >> 3);
      int rg = rowbase + r_;
      bool ok = (rg < n) && (ks < 5 || c_ == 0);
      const void* s = ok ? (const void*)(x + (size_t)rg * 164 + ks * 32 + c_ * 4)
                         : (const void*)zp;
      GLOAD_LDS16(s, &sAi[w][buf][j * 256]);
    }
  };

  f32x4 acc[CT];
#pragma unroll
  for (int c = 0; c < CT; c++) acc[c] = (f32x4)0.0f;

  int rr = lane & 15;
  int c0 = (lane >> 4) * 2;
  int s0 = c0 ^ (rr & 7);
  int s1 = (c0 + 1) ^ (rr & 7);

  f16x8 bfr[2][CT];
  stage(0, 0);
  stage(1, 1);
#pragma unroll
  for (int c = 0; c < CT; c++) bfr[0][c] = Bf[c * 64 + lane];

  auto step = [&](auto ksc, auto wnc) {
    constexpr int ks = decltype(ksc)::value;
    constexpr int WN = decltype(wnc)::value;
    if constexpr (ks + 1 < 6) {
#pragma unroll
      for (int c = 0; c < CT; c++)
        bfr[(ks + 1) & 1][c] = Bf[((ks + 1) * CT + c) * 64 + lane];
    }
    if constexpr (ks + 2 < 6) stage(ks + 2, (ks + 2) % 3);
    wait_vm<WN>();
    const float* bp = &sAi[w][ks % 3][0];
    float4 u0 = *(const float4*)&bp[rr * 32 + s0 * 4];
    float4 u1 = *(const float4*)&bp[rr * 32 + s1 * 4];
    float v[8] = {u0.x, u0.y, u0.z, u0.w, u1.x, u1.y, u1.z, u1.w};
    f16x8 ah;
#pragma unroll
    for (int i = 0; i < 8; i++) ah[i] = (_Float16)v[i];
#pragma unroll
    for (int c = 0; c < CT; c++)
      acc[c] = __builtin_amdgcn_mfma_f32_16x16x32_f16(ah, bfr[ks & 1][c], acc[c], 0, 0, 0);
  };
  step(IC<0>{}, IC<10>{});
  step(IC<1>{}, IC<12>{});
  step(IC<2>{}, IC<12>{});
  step(IC<3>{}, IC<12>{});
  step(IC<4>{}, IC<10>{});
  step(IC<5>{}, IC<0>{});

  // bias + relu + LN (row lives in a 16-lane group; wave-local)
  int r0 = (lane >> 4) * 4;
  int li = lane & 15;
  float s1v[4] = {0, 0, 0, 0}, s2v[4] = {0, 0, 0, 0};
#pragma unroll
  for (int c = 0; c < CT; c++) {
    float bb = bias[c * 16 + li];
#pragma unroll
    for (int r = 0; r < 4; r++) {
      float t = acc[c][r] + bb;
      t = t > 0.0f ? t : 0.0f;
      acc[c][r] = t;
      s1v[r] += t;
      s2v[r] += t * t;
    }
  }
#pragma unroll
  for (int m = 1; m < 16; m <<= 1) {
#pragma unroll
    for (int r = 0; r < 4; r++) {
      s1v[r] += __shfl_xor(s1v[r], m);
      s2v[r] += __shfl_xor(s2v[r], m);
    }
  }
  // repack h into wave LDS (swizzled 16x128 f16 = 4KB), store coalesced
  wait_lgkm0();
  _Float16* lr = (_Float16*)&sAi[w][0][0];
#pragma unroll
  for (int c = 0; c < CT; c++) {
    float gv = gamma[c * 16 + li], bv = beta[c * 16 + li];
#pragma unroll
    for (int r = 0; r < 4; r++) {
      float mean = s1v[r] * (1.0f / N);
      float var = s2v[r] * (1.0f / N) - mean * mean;
      float rs = rsqrtf(var + 1e-5f);
      lr[swz(r0 + r, c * 16 + li)] =
          (_Float16)((acc[c][r] - mean) * rs * gv + bv);
    }
  }
  wait_lgkm0();
#pragma unroll
  for (int i = 0; i < 4; i++) {
    int chunk = i * 64 + lane;
    int rloc = chunk >> 4;
    int cc = chunk & 15;
    if (rowbase + rloc < n)
      *(f16x8*)&outH[(size_t)(rowbase + rloc) * 128 + cc * 8] =
          *(const f16x8*)&lr[swz(rloc, cc * 8)];
  }

  // ---- phase 2: xw1 = h @ Wg1 (A from swizzled LDS; B software-pipelined)
  int kof = (lane >> 4) * 8;
  f16x8 b1a[CT], b1b[CT];
#pragma unroll
  for (int c = 0; c < CT; c++) b1a[c] = Bf1[c * 64 + lane];  // B1[0]
#pragma unroll
  for (int c = 0; c < CT; c++) acc[c] = (f32x4)0.0f;

  // ks = 0
#pragma unroll
  for (int c = 0; c < CT; c++) b1b[c] = Bf1[(1 * CT + c) * 64 + lane];  // B1[1]
  wait_vm<8>();
  {
    f16x8 av = *(const f16x8*)&lr[swz(rr, 0 * 32 + kof)];
#pragma unroll
    for (int c = 0; c < CT; c++)
      acc[c] = __builtin_amdgcn_mfma_f32_16x16x32_f16(av, b1a[c], acc[c], 0, 0, 0);
  }
  // ks = 1
#pragma unroll
  for (int c = 0; c < CT; c++) b1a[c] = Bf1[(2 * CT + c) * 64 + lane];  // B1[2]
  wait_vm<8>();
  {
    f16x8 av = *(const f16x8*)&lr[swz(rr, 1 * 32 + kof)];
#pragma unroll
    for (int c = 0; c < CT; c++)
      acc[c] = __builtin_amdgcn_mfma_f32_16x16x32_f16(av, b1b[c], acc[c], 0, 0, 0);
  }
  // ks = 2
#pragma unroll
  for (int c = 0; c < CT; c++) b1b[c] = Bf1[(3 * CT + c) * 64 + lane];  // B1[3]
  wait_vm<8>();
  {
    f16x8 av = *(const f16x8*)&lr[swz(rr, 2 * 32 + kof)];
#pragma unroll
    for (int c = 0; c < CT; c++)
      acc[c] = __builtin_amdgcn_mfma_f32_16x16x32_f16(av, b1a[c], acc[c], 0, 0, 0);
  }
  // ks = 3
  wait_vm<0>();
  {
    f16x8 av = *(const f16x8*)&lr[swz(rr, 3 * 32 + kof)];
#pragma unroll
    for (int c = 0; c < CT; c++)
      acc[c] = __builtin_amdgcn_mfma_f32_16x16x32_f16(av, b1b[c], acc[c], 0, 0, 0);
  }

  // repack xw1 + coalesced store
  wait_lgkm0();
#pragma unroll
  for (int c = 0; c < CT; c++) {
#pragma unroll
    for (int r = 0; r < 4; r++)
      lr[swz(r0 + r, c * 16 + li)] = (_Float16)acc[c][r];
  }
  wait_lgkm0();
#pragma unroll
  for (int i = 0; i < 4; i++) {
    int chunk = i * 64 + lane;
    int rloc = chunk >> 4;
    int cc = chunk & 15;
    if (rowbase + rloc < n)
      *(f16x8*)&outXW[(size_t)(rowbase + rloc) * 128 + cc * 8] =
          *(const f16x8*)&lr[swz(rloc, cc * 8)];
  }
}

// ---------------- conv GEMM: xw = A@W (64 rows, 4 waves) -------------------
template <int K, int N>
__global__ __launch_bounds__(256, 4) void k_gemm_f16(
    const _Float16* __restrict__ A, const _Float16* __restrict__ pB,
    const float* __restrict__ zp, _Float16* __restrict__ out, int n) {
  constexpr int KS = K / 32, CT = N / 16;
  __shared__ __align__(16) _Float16 sB[KS * CT * 512];
  __shared__ __align__(16) _Float16 sA[4][KS][512];
  int tid = threadIdx.x;
  int lane = tid & 63, w = tid >> 6;
  int rowbase = blockIdx.x * 64 + w * 16;

  for (int u = w; u < KS * CT; u += 4)
    GLOAD_LDS16(pB + (size_t)u * 512 + lane * 8, &sB[(size_t)u * 512]);

  int r_ = lane >> 2;
  int c_ = (lane & 3) ^ ((r_ >> 1) & 3);
  int rg = rowbase + r_;
  bool rok = rg < n;
  for (int ks = 0; ks < KS; ks++) {
    const void* s = rok ? (const void*)(A + (size_t)rg * K + ks * 32 + c_ * 8)
                        : (const void*)zp;
    GLOAD_LDS16(s, &sA[w][ks][0]);
  }
  wait_vm<KS>();
  __builtin_amdgcn_s_barrier();

  f32x4 acc[CT];
#pragma unroll
  for (int c = 0; c < CT; c++) acc[c] = (f32x4)0.0f;

  int rr = lane & 15;
  int slot = (lane >> 4) ^ ((rr >> 1) & 3);

  auto cstep = [&](auto ksc) {
    constexpr int ks = decltype(ksc)::value;
    wait_vm<KS - 1 - ks>();
    f16x8 av = *(const f16x8*)&sA[w][ks][rr * 32 + slot * 8];
#pragma unroll
    for (int c = 0; c < CT; c++) {
      f16x8 b = *(const f16x8*)&sB[(size_t)(ks * CT + c) * 512 + lane * 8];
      acc[c] = __builtin_amdgcn_mfma_f32_16x16x32_f16(av, b, acc[c], 0, 0, 0);
    }
  };
  cstep(IC<0>{});
  if constexpr (KS > 1) cstep(IC<1>{});
  if constexpr (KS > 2) cstep(IC<2>{});
  if constexpr (KS > 3) cstep(IC<3>{});

  int r0 = (lane >> 4) * 4;
  int li = lane & 15;
  wait_lgkm0();
  _Float16* lr = &sA[w][0][0];
#pragma unroll
  for (int c = 0; c < CT; c++) {
#pragma unroll
    for (int r = 0; r < 4; r++)
      lr[swzN<N>(r0 + r, c * 16 + li)] = (_Float16)acc[c][r];
  }
  wait_lgkm0();
#pragma unroll
  for (int i = 0; i < N / 32; i++) {
    int chunk = i * 64 + lane;
    int rloc = chunk / (N / 8);
    int cc = chunk % (N / 8);
    if (rowbase + rloc < n)
      *(f16x8*)&out[(size_t)(rowbase + rloc) * N + cc * 8] =
          *(const f16x8*)&lr[swzN<N>(rloc, cc * 8)];
  }
}

// ---------------- gather, 8 cols/thread (f16x8), 8-deep batches ------------
template <int OUT_D, int MODE>
__global__ __launch_bounds__(256, 4) void k_gather8(
    const int* __restrict__ off, const int2* __restrict__ csr,
    const _Float16* __restrict__ xw, const float* __restrict__ dinv,
    const float* __restrict__ bias, const _Float16* __restrict__ auxh,
    const float* __restrict__ gamma, const float* __restrict__ beta,
    _Float16* __restrict__ out, int n) {
  constexpr int TPN = OUT_D / 8;
  constexpr int NPB = 256 / TPN;
  int tid = threadIdx.x;
  int node = blockIdx.x * NPB + tid / TPN;
  int li = tid % TPN;
  if (node >= n) return;
  int start = off[node], end = off[node + 1];
  float di = dinv[node];
  float d2 = di * di;
  const _Float16* xp = xw + 8 * li;
  f16x8 self = *(const f16x8*)(xp + (size_t)node * OUT_D);
  f16x8 hres;
  if constexpr (MODE == 0)
    hres = *(const f16x8*)(auxh + (size_t)node * OUT_D + 8 * li);
  float a[8];
#pragma unroll
  for (int q = 0; q < 8; q++) a[q] = (float)self[q] * d2 + bias[8 * li + q];
  for (int cb = start; cb < end; cb += TPN) {
    int m = end - cb; if (m > TPN) m = TPN;
    int sv = node; float nv = 0.0f;
    if (li < m) { int2 me = csr[cb + li]; sv = me.x; nv = __int_as_float(me.y); }
    for (int j0 = 0; j0 < m; j0 += 8) {
      int s[8]; float wv[8];
#pragma unroll
      for (int q = 0; q < 8; q++) {
        s[q] = __shfl(sv, j0 + q, TPN);
        wv[q] = __shfl(nv, j0 + q, TPN);
      }
      f16x8 v[8];
#pragma unroll
      for (int q = 0; q < 8; q++) v[q] = *(const f16x8*)(xp + (size_t)s[q] * OUT_D);
#pragma unroll
      for (int q = 0; q < 8; q++) {
#pragma unroll
        for (int c = 0; c < 8; c++) a[c] += (float)v[q][c] * wv[q];
      }
    }
  }
  _Float16* po = out + (size_t)node * OUT_D + 8 * li;
  if constexpr (MODE == 0) {
    f16x8 o;
#pragma unroll
    for (int q = 0; q < 8; q++)
      o[q] = (_Float16)((a[q] > 0.0f ? a[q] : 0.0f) + (float)hres[q]);
    *(f16x8*)po = o;
  } else {
    float s1 = 0.0f, s2 = 0.0f;
#pragma unroll
    for (int q = 0; q < 8; q++) {
      a[q] = a[q] > 0.0f ? a[q] : 0.0f;
      s1 += a[q];
      s2 += a[q] * a[q];
    }
#pragma unroll
    for (int d = 1; d < TPN; d <<= 1) {
      s1 += __shfl_xor(s1, d, TPN);
      s2 += __shfl_xor(s2, d, TPN);
    }
    float m_ = s1 * (1.0f / OUT_D);
    float var = s2 * (1.0f / OUT_D) - m_ * m_;
    float rs = rsqrtf(var + 1e-5f);
    f16x8 o;
#pragma unroll
    for (int q = 0; q < 8; q++)
      o[q] = (_Float16)((a[q] - m_) * rs * gamma[8 * li + q] + beta[8 * li + q]);
    *(f16x8*)po = o;
  }
}

// ---------------- conv3 gather, 4 cols/thread (TPN=8) ----------------------
__global__ __launch_bounds__(256, 4) void k_gather3(
    const int* __restrict__ off, const int2* __restrict__ csr,
    const _Float16* __restrict__ xw, const float* __restrict__ dinv,
    const float* __restrict__ bias, _Float16* __restrict__ out, int n) {
  constexpr int OUT_D = 32, TPN = 8, NPB = 32;
  int tid = threadIdx.x;
  int node = blockIdx.x * NPB + tid / TPN;
  int li = tid % TPN;
  if (node >= n) return;
  int start = off[node], end = off[node + 1];
  float di = dinv[node];
  float d2 = di * di;
  const _Float16* xp = xw + 4 * li;
  f16x4 self = *(const f16x4*)(xp + (size_t)node * OUT_D);
  float a0 = (float)self[0] * d2 + bias[4 * li + 0];
  float a1 = (float)self[1] * d2 + bias[4 * li + 1];
  float a2 = (float)self[2] * d2 + bias[4 * li + 2];
  float a3 = (float)self[3] * d2 + bias[4 * li + 3];
  for (int cb = start; cb < end; cb += TPN) {
    int m = end - cb; if (m > TPN) m = TPN;
    int sv = node; float nv = 0.0f;
    if (li < m) { int2 me = csr[cb + li]; sv = me.x; nv = __int_as_float(me.y); }
    for (int j0 = 0; j0 < m; j0 += 8) {
      int s[8]; float wv[8];
#pragma unroll
      for (int q = 0; q < 8; q++) {
        s[q] = __shfl(sv, j0 + q, TPN);
        wv[q] = __shfl(nv, j0 + q, TPN);
      }
      f16x4 v[8];
#pragma unroll
      for (int q = 0; q < 8; q++) v[q] = *(const f16x4*)(xp + (size_t)s[q] * OUT_D);
#pragma unroll
      for (int q = 0; q < 8; q++) {
        a0 += (float)v[q][0] * wv[q];
        a1 += (float)v[q][1] * wv[q];
        a2 += (float)v[q][2] * wv[q];
        a3 += (float)v[q][3] * wv[q];
      }
    }
  }
  f16x4 o;
  o[0] = (_Float16)a0; o[1] = (_Float16)a1;
  o[2] = (_Float16)a2; o[3] = (_Float16)a3;
  *(f16x4*)(out + (size_t)node * OUT_D + 4 * li) = o;
}

// ---------------- tail: relu(agg3) -> Wv -> Wo -> Wc1 -> Wc2 -> Wc3 --------
__global__ __launch_bounds__(256) void k_tail(
    const _Float16* __restrict__ agg3, const float* __restrict__ Wv,
    const float* __restrict__ bv, const float* __restrict__ Wo,
    const float* __restrict__ bo, const float* __restrict__ Wc1,
    const float* __restrict__ bc1, const float* __restrict__ Wc2,
    const float* __restrict__ bc2, const float* __restrict__ Wc3,
    const float* __restrict__ bc3, float* __restrict__ out, int n) {
  __shared__ float sWv[1024], sWo[1024], sWc1[512], sWc2[512];
  __shared__ float sbv[32], sbo[32], sbc2[32], sWc3[32], sbc1[16], sbc3[1];
  int tid = threadIdx.x;
  for (int i = tid; i < 1024; i += 256) { sWv[i] = Wv[i]; sWo[i] = Wo[i]; }
  for (int i = tid; i < 512; i += 256) { sWc1[i] = Wc1[i]; sWc2[i] = Wc2[i]; }
  if (tid < 32) { sbv[tid] = bv[tid]; sbo[tid] = bo[tid];
                  sbc2[tid] = bc2[tid]; sWc3[tid] = Wc3[tid]; }
  if (tid < 16) sbc1[tid] = bc1[tid];
  if (tid == 0) sbc3[0] = bc3[0];
  __syncthreads();
  int node = blockIdx.x * blockDim.x + tid;
  if (node >= n) return;
  float a[32];
  const f16x8* row8 = (const f16x8*)(agg3 + (size_t)node * 32);
#pragma unroll
  for (int q = 0; q < 4; q++) {
    f16x8 t = row8[q];
#pragma unroll
    for (int i = 0; i < 8; i++) {
      float f = (float)t[i];
      a[8 * q + i] = f > 0.0f ? f : 0.0f;
    }
  }
  float v[32];
#pragma unroll
  for (int j = 0; j < 32; j++) v[j] = sbv[j];
  for (int k = 0; k < 32; k++) {
#pragma unroll
    for (int j = 0; j < 32; j++) v[j] += a[k] * sWv[k * 32 + j];
  }
  float o[32];
#pragma unroll
  for (int j = 0; j < 32; j++) o[j] = sbo[j];
  for (int k = 0; k < 32; k++) {
#pragma unroll
    for (int j = 0; j < 32; j++) o[j] += v[k] * sWo[k * 32 + j];
  }
  float c1[16];
#pragma unroll
  for (int j = 0; j < 16; j++) c1[j] = sbc1[j];
  for (int k = 0; k < 32; k++) {
#pragma unroll
    for (int j = 0; j < 16; j++) c1[j] += o[k] * sWc1[k * 16 + j];
  }
#pragma unroll
  for (int j = 0; j < 16; j++) c1[j] = c1[j] > 0.0f ? c1[j] : 0.0f;
  float c2[32];
#pragma unroll
  for (int j = 0; j < 32; j++) c2[j] = sbc2[j];
  for (int k = 0; k < 16; k++) {
#pragma unroll
    for (int j = 0; j < 32; j++) c2[j] += c1[k] * sWc2[k * 32 + j];
  }
  float r = sbc3[0];
#pragma unroll
  for (int k = 0; k < 32; k++) {
    float c = c2[k] > 0.0f ? c2[k] : 0.0f;
    r += c * sWc3[k];
  }
  out[node] = r;
}

// ---------------------------------------------------------------------------
extern "C" void kernel_launch(void* const* d_in, const int* in_sizes, int n_in,
                              void* d_out, int out_size, void* d_ws, size_t ws_size,
                              hipStream_t stream) {
  const float* x   = (const float*)d_in[0];
  const int* ei    = (const int*)d_in[1];
  const float* Wi  = (const float*)d_in[2];
  const float* bi  = (const float*)d_in[3];
  const float* g1  = (const float*)d_in[4];
  const float* b1  = (const float*)d_in[5];
  const float* Wg1 = (const float*)d_in[6];
  const float* bg1 = (const float*)d_in[7];
  const float* Wg2 = (const float*)d_in[8];
  const float* bg2 = (const float*)d_in[9];
  const float* g2  = (const float*)d_in[10];
  const float* b2  = (const float*)d_in[11];
  const float* Wg3 = (const float*)d_in[12];
  const float* bg3 = (const float*)d_in[13];
  // d_in[14..17]: Wq,bq,Wk,bk — mathematically dead (softmax over 1 key == 1)
  const float* Wv  = (const float*)d_in[18];
  const float* bv  = (const float*)d_in[19];
  const float* Wo  = (const float*)d_in[20];
  const float* bo  = (const float*)d_in[21];
  const float* Wc1 = (const float*)d_in[22];
  const float* bc1 = (const float*)d_in[23];
  const float* Wc2 = (const float*)d_in[24];
  const float* bc2 = (const float*)d_in[25];
  const float* Wc3 = (const float*)d_in[26];
  const float* bc3 = (const float*)d_in[27];

  const int n = in_sizes[0] / 164;
  const int e = in_sizes[1] / 2;
  const int* src = ei;
  const int* dst = ei + e;

  // workspace layout (256B aligned)
  char* ws = (char*)d_ws;
  size_t off = 0;
  auto alloc = [&](size_t bytes) {
    char* p = ws + off;
    off += (bytes + 255) & ~(size_t)255;
    return p;
  };
  _Float16* A     = (_Float16*)alloc((size_t)n * 128 * 2);
  _Float16* B     = (_Float16*)alloc((size_t)n * 128 * 2);
  _Float16* C     = (_Float16*)alloc((size_t)n * 128 * 2);
  float* dinv     = (float*)alloc((size_t)n * 4);
  int*   counts   = (int*)alloc((size_t)n * 4);
  int*   offsets  = (int*)alloc((size_t)(n + 1) * 4);
  int*   bsums    = (int*)alloc(256 * 4);
  int2*  csr      = (int2*)alloc((size_t)e * 8);
  _Float16* pWi   = (_Float16*)alloc(3072 * 16);
  _Float16* pWg1  = (_Float16*)alloc(2048 * 16);
  _Float16* pWg2  = (_Float16*)alloc(1024 * 16);
  _Float16* pWg3  = (_Float16*)alloc(256 * 16);
  float* zp       = (float*)alloc(64 * 4);
  (void)ws_size;

  const int BS = 256;
  const int SB = (n + 1023) / 1024;
  const int GB = (n + 63) / 64;   // 64-row gemm blocks (1563)

  // ---- setup ----
  k_setup<<<25 + (n + 255) / 256, 256, 0, stream>>>(
      Wi, Wg1, Wg2, Wg3, pWi, pWg1, pWg2, pWg3, counts, zp, n);

  // ---- CSR build ----
  k_count<<<(e + BS - 1) / BS, BS, 0, stream>>>(dst, counts, e);
  k_scan_part<<<SB, 256, 0, stream>>>(counts, bsums, n);
  k_scan_down<<<SB, 256, 0, stream>>>(counts, bsums, offsets, dinv, n, e, SB);
  k_fill<<<(e + BS - 1) / BS, BS, 0, stream>>>(src, dst, offsets, counts, dinv,
                                               csr, e);

  // ---- fused input + conv1 GEMM: A = h, B = xw1 ----
  k_gemm_in1<<<GB, 256, 0, stream>>>(x, pWi, pWg1, bi, g1, b1, zp, A, B, n);

  // ---- conv1 gather -> C = h1 = relu(agg)+h ----
  k_gather8<128, 0><<<(n + 15) / 16, 256, 0, stream>>>(
      offsets, csr, B, dinv, bg1, A, nullptr, nullptr, C, n);

  // ---- conv2 ----
  k_gemm_f16<128, 64><<<GB, 256, 0, stream>>>(C, pWg2, zp, A, n);
  k_gather8<64, 1><<<(n + 31) / 32, 256, 0, stream>>>(
      offsets, csr, A, dinv, bg2, nullptr, g2, b2, B, n);

  // ---- conv3 ----
  k_gemm_f16<64, 32><<<GB, 256, 0, stream>>>(B, pWg3, zp, A, n);
  k_gather3<<<(n + 31) / 32, 256, 0, stream>>>(
      offsets, csr, A, dinv, bg3, C, n);

  // ---- tail ----
  k_tail<<<(n + BS - 1) / BS, BS, 0, stream>>>(
      C, Wv, bv, Wo, bo, Wc1, bc1, Wc2, bc2, Wc3, bc3, (float*)d_out, n);
}

// Round 19
// 206.437 us; speedup vs baseline: 1.7790x; 1.0658x over previous
//
#include <hip/hip_runtime.h>

// ---------------------------------------------------------------------------
// EnhancedBitcoinGCN: 3x GCNConv + LN/residual + (trivial) MHA + MLP head
// Round 18 -> 19 (restore best-known r16 configuration):
//  * r17/r18 both regressed via register spill: the compiler pins k_gemm_in1
//    at 64 VGPRs (ignores launch_bounds headroom) and spills the phase-2 B
//    double-buffer to scratch (FETCH 38->68MB, WRITE 56->112MB).
//  * r16's phase-2 (single b1 buffer, vmcnt(0) per K-step) fits in 64 VGPRs
//    with zero spill: 206.7us total, the session best. Restored verbatim.
//  * Final structure: CSR build (5 kernels) + fused input/conv1 MFMA GEMM
//    (DMA-pipelined, swizzled LDS repack, coalesced f16x8 stores) + conv2/3
//    GEMMs (full-depth DMA pipeline, B staged once) + 3 latency-optimized
//    gathers (8-deep batches) + fused MLP tail. fp16 intermediates.
// ---------------------------------------------------------------------------

typedef __attribute__((ext_vector_type(8))) _Float16 f16x8;
typedef __attribute__((ext_vector_type(4))) _Float16 f16x4;
typedef __attribute__((ext_vector_type(4))) float f32x4;

template <int V> struct IC { static constexpr int value = V; };

#define GLOAD_LDS16(gp, lp)                                        \
  __builtin_amdgcn_global_load_lds(                                \
      (const __attribute__((address_space(1))) void*)(gp),         \
      (__attribute__((address_space(3))) void*)(lp), 16, 0, 0)

template <int NV>
static __device__ __forceinline__ void wait_vm() {
  asm volatile("s_waitcnt vmcnt(%0)" :: "n"(NV) : "memory");
}
static __device__ __forceinline__ void wait_lgkm0() {
  asm volatile("s_waitcnt lgkmcnt(0)" ::: "memory");
  __builtin_amdgcn_sched_barrier(0);
}

// swizzled element index within a 16-row x NC-col f16 repack tile
static __device__ __forceinline__ int swz(int row, int col) {
  return row * 128 + (col ^ ((row & 7) << 3));   // NC=128 tiles
}
template <int NC>
static __device__ __forceinline__ int swzN(int row, int col) {
  return row * NC + (col ^ (((row & 7) << 3) & (NC - 1)));
}

// ---------------- CSR build ----------------
__global__ void k_count(const int* __restrict__ dst, int* __restrict__ counts, int e) {
  int i = blockIdx.x * blockDim.x + threadIdx.x;
  if (i < e) atomicAdd(&counts[dst[i]], 1);
}

__global__ __launch_bounds__(256) void k_scan_part(
    const int* __restrict__ counts, int* __restrict__ bsums, int n) {
  int tid = threadIdx.x;
  int i0 = blockIdx.x * 1024 + tid * 4;
  int s = 0;
#pragma unroll
  for (int k = 0; k < 4; k++) { int i = i0 + k; if (i < n) s += counts[i]; }
#pragma unroll
  for (int d = 1; d < 64; d <<= 1) s += __shfl_xor(s, d);
  __shared__ int wsum[4];
  int lane = tid & 63, w = tid >> 6;
  if (lane == 0) wsum[w] = s;
  __syncthreads();
  if (tid == 0) bsums[blockIdx.x] = wsum[0] + wsum[1] + wsum[2] + wsum[3];
}

__global__ __launch_bounds__(256) void k_scan_down(
    int* __restrict__ counts, const int* __restrict__ bsums,
    int* __restrict__ offsets, float* __restrict__ dinv, int n, int e, int nb) {
  int tid = threadIdx.x;
  int lane = tid & 63, w = tid >> 6;
  __shared__ int wsum[4], psum[4];
  int pv = (tid < nb && tid < blockIdx.x) ? bsums[tid] : 0;
#pragma unroll
  for (int d = 1; d < 64; d <<= 1) pv += __shfl_xor(pv, d);
  if (lane == 0) psum[w] = pv;
  __syncthreads();
  int blockpref = psum[0] + psum[1] + psum[2] + psum[3];

  int i0 = blockIdx.x * 1024 + tid * 4;
  int c[4]; int tsum = 0;
#pragma unroll
  for (int k = 0; k < 4; k++) { int i = i0 + k; c[k] = (i < n) ? counts[i] : 0; tsum += c[k]; }
  int v = tsum;
#pragma unroll
  for (int d = 1; d < 64; d <<= 1) { int t = __shfl_up(v, d); if (lane >= d) v += t; }
  if (lane == 63) wsum[w] = v;
  __syncthreads();
  int wadd = 0;
#pragma unroll
  for (int q = 0; q < 4; q++) if (q < w) wadd += wsum[q];
  int run = (v - tsum) + wadd + blockpref;
#pragma unroll
  for (int k = 0; k < 4; k++) {
    int i = i0 + k;
    if (i < n) {
      offsets[i] = run;
      dinv[i] = rsqrtf((float)(c[k] + 1));
      counts[i] = 0;
    }
    run += c[k];
  }
  if (blockIdx.x == 0 && tid == 0) offsets[n] = e;
}

__global__ void k_fill(const int* __restrict__ src, const int* __restrict__ dst,
                       const int* __restrict__ offsets, int* __restrict__ cursor,
                       const float* __restrict__ dinv, int2* __restrict__ csr, int e) {
  int i = blockIdx.x * blockDim.x + threadIdx.x;
  if (i >= e) return;
  int s = src[i], d = dst[i];
  int pos = atomicAdd(&cursor[d], 1);
  csr[offsets[d] + pos] = make_int2(s, __float_as_int(dinv[s] * dinv[d]));
}

// ---------------- weight prepack (fragment-ordered fp16, hi only) ----------
__device__ __forceinline__ void pack_hi(const float* __restrict__ W,
                                        _Float16* __restrict__ dst,
                                        int K, int N, int u) {
  int lane = u & 63; int rest = u >> 6; int CT = N >> 4;
  int ct = rest % CT, ks = rest / CT;
  int gcol = ct * 16 + (lane & 15);
  int gk0 = ks * 32 + (lane >> 4) * 8;
  size_t o = (size_t)(ks * CT + ct) * 512 + lane * 8;
#pragma unroll
  for (int i = 0; i < 8; i++) {
    float v = (gk0 + i < K) ? W[(size_t)(gk0 + i) * N + gcol] : 0.0f;
    dst[o + i] = (_Float16)v;
  }
}

__global__ void k_setup(const float* __restrict__ Wi, const float* __restrict__ Wg1,
                        const float* __restrict__ Wg2, const float* __restrict__ Wg3,
                        _Float16* __restrict__ pWi, _Float16* __restrict__ pWg1,
                        _Float16* __restrict__ pWg2, _Float16* __restrict__ pWg3,
                        int* __restrict__ counts, float* __restrict__ zp, int n) {
  int b = blockIdx.x;
  if (b < 25) {
    int t = b * 256 + threadIdx.x;
    if (t < 3072) pack_hi(Wi, pWi, 164, 128, t);
    else if (t < 5120) pack_hi(Wg1, pWg1, 128, 128, t - 3072);
    else if (t < 6144) pack_hi(Wg2, pWg2, 128, 64, t - 5120);
    else if (t < 6400) pack_hi(Wg3, pWg3, 64, 32, t - 6144);
  } else {
    if (b == 25 && threadIdx.x < 64) zp[threadIdx.x] = 0.0f;
    int i = (b - 25) * 256 + threadIdx.x;
    if (i < n) counts[i] = 0;
  }
}

// ---------------- fused input GEMM + conv1 GEMM (64 rows, 4 waves) ---------
__global__ __launch_bounds__(256, 4) void k_gemm_in1(
    const float* __restrict__ x, const _Float16* __restrict__ pB,
    const _Float16* __restrict__ pB1, const float* __restrict__ bias,
    const float* __restrict__ gamma, const float* __restrict__ beta,
    const float* __restrict__ zp, _Float16* __restrict__ outH,
    _Float16* __restrict__ outXW, int n) {
  constexpr int N = 128, CT = 8;
  __shared__ __align__(16) float sAi[4][3][512];  // 4 waves x 3 ring x 2KB
  int tid = threadIdx.x;
  int lane = tid & 63, w = tid >> 6;
  int rowbase = blockIdx.x * 64 + w * 16;
  const f16x8* Bf = (const f16x8*)pB;
  const f16x8* Bf1 = (const f16x8*)pB1;

  auto stage = [&](int ks, int buf) {
#pragma unroll
    for (int j = 0; j < 2; j++) {
      int r_ = j * 8 + (lane >> 3);
      int c_ = (lane & 7) ^ (lane >> 3);
      int rg = rowbase + r_;
      bool ok = (rg < n) && (ks < 5 || c_ == 0);
      const void* s = ok ? (const void*)(x + (size_t)rg * 164 + ks * 32 + c_ * 4)
                         : (const void*)zp;
      GLOAD_LDS16(s, &sAi[w][buf][j * 256]);
    }
  };

  f32x4 acc[CT];
#pragma unroll
  for (int c = 0; c < CT; c++) acc[c] = (f32x4)0.0f;

  int rr = lane & 15;
  int c0 = (lane >> 4) * 2;
  int s0 = c0 ^ (rr & 7);
  int s1 = (c0 + 1) ^ (rr & 7);

  f16x8 bfr[2][CT];
  stage(0, 0);
  stage(1, 1);
#pragma unroll
  for (int c = 0; c < CT; c++) bfr[0][c] = Bf[c * 64 + lane];

  auto step = [&](auto ksc, auto wnc) {
    constexpr int ks = decltype(ksc)::value;
    constexpr int WN = decltype(wnc)::value;
    if constexpr (ks + 1 < 6) {
#pragma unroll
      for (int c = 0; c < CT; c++)
        bfr[(ks + 1) & 1][c] = Bf[((ks + 1) * CT + c) * 64 + lane];
    }
    if constexpr (ks + 2 < 6) stage(ks + 2, (ks + 2) % 3);
    wait_vm<WN>();
    const float* bp = &sAi[w][ks % 3][0];
    float4 u0 = *(const float4*)&bp[rr * 32 + s0 * 4];
    float4 u1 = *(const float4*)&bp[rr * 32 + s1 * 4];
    float v[8] = {u0.x, u0.y, u0.z, u0.w, u1.x, u1.y, u1.z, u1.w};
    f16x8 ah;
#pragma unroll
    for (int i = 0; i < 8; i++) ah[i] = (_Float16)v[i];
#pragma unroll
    for (int c = 0; c < CT; c++)
      acc[c] = __builtin_amdgcn_mfma_f32_16x16x32_f16(ah, bfr[ks & 1][c], acc[c], 0, 0, 0);
  };
  step(IC<0>{}, IC<10>{});
  step(IC<1>{}, IC<12>{});
  step(IC<2>{}, IC<12>{});
  step(IC<3>{}, IC<12>{});
  step(IC<4>{}, IC<10>{});
  step(IC<5>{}, IC<0>{});

  // bias + relu + LN (row lives in a 16-lane group; wave-local)
  int r0 = (lane >> 4) * 4;
  int li = lane & 15;
  float s1v[4] = {0, 0, 0, 0}, s2v[4] = {0, 0, 0, 0};
#pragma unroll
  for (int c = 0; c < CT; c++) {
    float bb = bias[c * 16 + li];
#pragma unroll
    for (int r = 0; r < 4; r++) {
      float t = acc[c][r] + bb;
      t = t > 0.0f ? t : 0.0f;
      acc[c][r] = t;
      s1v[r] += t;
      s2v[r] += t * t;
    }
  }
#pragma unroll
  for (int m = 1; m < 16; m <<= 1) {
#pragma unroll
    for (int r = 0; r < 4; r++) {
      s1v[r] += __shfl_xor(s1v[r], m);
      s2v[r] += __shfl_xor(s2v[r], m);
    }
  }
  // repack h into wave LDS (swizzled 16x128 f16 = 4KB), store coalesced
  wait_lgkm0();
  _Float16* lr = (_Float16*)&sAi[w][0][0];
#pragma unroll
  for (int c = 0; c < CT; c++) {
    float gv = gamma[c * 16 + li], bv = beta[c * 16 + li];
#pragma unroll
    for (int r = 0; r < 4; r++) {
      float mean = s1v[r] * (1.0f / N);
      float var = s2v[r] * (1.0f / N) - mean * mean;
      float rs = rsqrtf(var + 1e-5f);
      lr[swz(r0 + r, c * 16 + li)] =
          (_Float16)((acc[c][r] - mean) * rs * gv + bv);
    }
  }
  wait_lgkm0();
#pragma unroll
  for (int i = 0; i < 4; i++) {
    int chunk = i * 64 + lane;
    int rloc = chunk >> 4;
    int cc = chunk & 15;
    if (rowbase + rloc < n)
      *(f16x8*)&outH[(size_t)(rowbase + rloc) * 128 + cc * 8] =
          *(const f16x8*)&lr[swz(rloc, cc * 8)];
  }

  // ---- phase 2: xw1 = h @ Wg1 (A from swizzled LDS, B per-step from L2) ---
  int kof = (lane >> 4) * 8;
#pragma unroll
  for (int c = 0; c < CT; c++) acc[c] = (f32x4)0.0f;
#pragma unroll
  for (int ks = 0; ks < 4; ks++) {
    f16x8 b1[CT];
#pragma unroll
    for (int c = 0; c < CT; c++) b1[c] = Bf1[(ks * CT + c) * 64 + lane];
    f16x8 av = *(const f16x8*)&lr[swz(rr, ks * 32 + kof)];  // 2-way (free)
    wait_vm<0>();
#pragma unroll
    for (int c = 0; c < CT; c++)
      acc[c] = __builtin_amdgcn_mfma_f32_16x16x32_f16(av, b1[c], acc[c], 0, 0, 0);
  }
  // repack xw1 + coalesced store
  wait_lgkm0();
#pragma unroll
  for (int c = 0; c < CT; c++) {
#pragma unroll
    for (int r = 0; r < 4; r++)
      lr[swz(r0 + r, c * 16 + li)] = (_Float16)acc[c][r];
  }
  wait_lgkm0();
#pragma unroll
  for (int i = 0; i < 4; i++) {
    int chunk = i * 64 + lane;
    int rloc = chunk >> 4;
    int cc = chunk & 15;
    if (rowbase + rloc < n)
      *(f16x8*)&outXW[(size_t)(rowbase + rloc) * 128 + cc * 8] =
          *(const f16x8*)&lr[swz(rloc, cc * 8)];
  }
}

// ---------------- conv GEMM: xw = A@W (64 rows, 4 waves) -------------------
template <int K, int N>
__global__ __launch_bounds__(256, 4) void k_gemm_f16(
    const _Float16* __restrict__ A, const _Float16* __restrict__ pB,
    const float* __restrict__ zp, _Float16* __restrict__ out, int n) {
  constexpr int KS = K / 32, CT = N / 16;
  __shared__ __align__(16) _Float16 sB[KS * CT * 512];
  __shared__ __align__(16) _Float16 sA[4][KS][512];
  int tid = threadIdx.x;
  int lane = tid & 63, w = tid >> 6;
  int rowbase = blockIdx.x * 64 + w * 16;

  for (int u = w; u < KS * CT; u += 4)
    GLOAD_LDS16(pB + (size_t)u * 512 + lane * 8, &sB[(size_t)u * 512]);

  int r_ = lane >> 2;
  int c_ = (lane & 3) ^ ((r_ >> 1) & 3);
  int rg = rowbase + r_;
  bool rok = rg < n;
  for (int ks = 0; ks < KS; ks++) {
    const void* s = rok ? (const void*)(A + (size_t)rg * K + ks * 32 + c_ * 8)
                        : (const void*)zp;
    GLOAD_LDS16(s, &sA[w][ks][0]);
  }
  wait_vm<KS>();
  __builtin_amdgcn_s_barrier();

  f32x4 acc[CT];
#pragma unroll
  for (int c = 0; c < CT; c++) acc[c] = (f32x4)0.0f;

  int rr = lane & 15;
  int slot = (lane >> 4) ^ ((rr >> 1) & 3);

  auto cstep = [&](auto ksc) {
    constexpr int ks = decltype(ksc)::value;
    wait_vm<KS - 1 - ks>();
    f16x8 av = *(const f16x8*)&sA[w][ks][rr * 32 + slot * 8];
#pragma unroll
    for (int c = 0; c < CT; c++) {
      f16x8 b = *(const f16x8*)&sB[(size_t)(ks * CT + c) * 512 + lane * 8];
      acc[c] = __builtin_amdgcn_mfma_f32_16x16x32_f16(av, b, acc[c], 0, 0, 0);
    }
  };
  cstep(IC<0>{});
  if constexpr (KS > 1) cstep(IC<1>{});
  if constexpr (KS > 2) cstep(IC<2>{});
  if constexpr (KS > 3) cstep(IC<3>{});

  int r0 = (lane >> 4) * 4;
  int li = lane & 15;
  wait_lgkm0();
  _Float16* lr = &sA[w][0][0];
#pragma unroll
  for (int c = 0; c < CT; c++) {
#pragma unroll
    for (int r = 0; r < 4; r++)
      lr[swzN<N>(r0 + r, c * 16 + li)] = (_Float16)acc[c][r];
  }
  wait_lgkm0();
#pragma unroll
  for (int i = 0; i < N / 32; i++) {
    int chunk = i * 64 + lane;
    int rloc = chunk / (N / 8);
    int cc = chunk % (N / 8);
    if (rowbase + rloc < n)
      *(f16x8*)&out[(size_t)(rowbase + rloc) * N + cc * 8] =
          *(const f16x8*)&lr[swzN<N>(rloc, cc * 8)];
  }
}

// ---------------- gather, 8 cols/thread (f16x8), 8-deep batches ------------
template <int OUT_D, int MODE>
__global__ __launch_bounds__(256, 4) void k_gather8(
    const int* __restrict__ off, const int2* __restrict__ csr,
    const _Float16* __restrict__ xw, const float* __restrict__ dinv,
    const float* __restrict__ bias, const _Float16* __restrict__ auxh,
    const float* __restrict__ gamma, const float* __restrict__ beta,
    _Float16* __restrict__ out, int n) {
  constexpr int TPN = OUT_D / 8;
  constexpr int NPB = 256 / TPN;
  int tid = threadIdx.x;
  int node = blockIdx.x * NPB + tid / TPN;
  int li = tid % TPN;
  if (node >= n) return;
  int start = off[node], end = off[node + 1];
  float di = dinv[node];
  float d2 = di * di;
  const _Float16* xp = xw + 8 * li;
  f16x8 self = *(const f16x8*)(xp + (size_t)node * OUT_D);
  f16x8 hres;
  if constexpr (MODE == 0)
    hres = *(const f16x8*)(auxh + (size_t)node * OUT_D + 8 * li);
  float a[8];
#pragma unroll
  for (int q = 0; q < 8; q++) a[q] = (float)self[q] * d2 + bias[8 * li + q];
  for (int cb = start; cb < end; cb += TPN) {
    int m = end - cb; if (m > TPN) m = TPN;
    int sv = node; float nv = 0.0f;
    if (li < m) { int2 me = csr[cb + li]; sv = me.x; nv = __int_as_float(me.y); }
    for (int j0 = 0; j0 < m; j0 += 8) {
      int s[8]; float wv[8];
#pragma unroll
      for (int q = 0; q < 8; q++) {
        s[q] = __shfl(sv, j0 + q, TPN);
        wv[q] = __shfl(nv, j0 + q, TPN);
      }
      f16x8 v[8];
#pragma unroll
      for (int q = 0; q < 8; q++) v[q] = *(const f16x8*)(xp + (size_t)s[q] * OUT_D);
#pragma unroll
      for (int q = 0; q < 8; q++) {
#pragma unroll
        for (int c = 0; c < 8; c++) a[c] += (float)v[q][c] * wv[q];
      }
    }
  }
  _Float16* po = out + (size_t)node * OUT_D + 8 * li;
  if constexpr (MODE == 0) {
    f16x8 o;
#pragma unroll
    for (int q = 0; q < 8; q++)
      o[q] = (_Float16)((a[q] > 0.0f ? a[q] : 0.0f) + (float)hres[q]);
    *(f16x8*)po = o;
  } else {
    float s1 = 0.0f, s2 = 0.0f;
#pragma unroll
    for (int q = 0; q < 8; q++) {
      a[q] = a[q] > 0.0f ? a[q] : 0.0f;
      s1 += a[q];
      s2 += a[q] * a[q];
    }
#pragma unroll
    for (int d = 1; d < TPN; d <<= 1) {
      s1 += __shfl_xor(s1, d, TPN);
      s2 += __shfl_xor(s2, d, TPN);
    }
    float m_ = s1 * (1.0f / OUT_D);
    float var = s2 * (1.0f / OUT_D) - m_ * m_;
    float rs = rsqrtf(var + 1e-5f);
    f16x8 o;
#pragma unroll
    for (int q = 0; q < 8; q++)
      o[q] = (_Float16)((a[q] - m_) * rs * gamma[8 * li + q] + beta[8 * li + q]);
    *(f16x8*)po = o;
  }
}

// ---------------- conv3 gather, 4 cols/thread (TPN=8) ----------------------
__global__ __launch_bounds__(256, 4) void k_gather3(
    const int* __restrict__ off, const int2* __restrict__ csr,
    const _Float16* __restrict__ xw, const float* __restrict__ dinv,
    const float* __restrict__ bias, _Float16* __restrict__ out, int n) {
  constexpr int OUT_D = 32, TPN = 8, NPB = 32;
  int tid = threadIdx.x;
  int node = blockIdx.x * NPB + tid / TPN;
  int li = tid % TPN;
  if (node >= n) return;
  int start = off[node], end = off[node + 1];
  float di = dinv[node];
  float d2 = di * di;
  const _Float16* xp = xw + 4 * li;
  f16x4 self = *(const f16x4*)(xp + (size_t)node * OUT_D);
  float a0 = (float)self[0] * d2 + bias[4 * li + 0];
  float a1 = (float)self[1] * d2 + bias[4 * li + 1];
  float a2 = (float)self[2] * d2 + bias[4 * li + 2];
  float a3 = (float)self[3] * d2 + bias[4 * li + 3];
  for (int cb = start; cb < end; cb += TPN) {
    int m = end - cb; if (m > TPN) m = TPN;
    int sv = node; float nv = 0.0f;
    if (li < m) { int2 me = csr[cb + li]; sv = me.x; nv = __int_as_float(me.y); }
    for (int j0 = 0; j0 < m; j0 += 8) {
      int s[8]; float wv[8];
#pragma unroll
      for (int q = 0; q < 8; q++) {
        s[q] = __shfl(sv, j0 + q, TPN);
        wv[q] = __shfl(nv, j0 + q, TPN);
      }
      f16x4 v[8];
#pragma unroll
      for (int q = 0; q < 8; q++) v[q] = *(const f16x4*)(xp + (size_t)s[q] * OUT_D);
#pragma unroll
      for (int q = 0; q < 8; q++) {
        a0 += (float)v[q][0] * wv[q];
        a1 += (float)v[q][1] * wv[q];
        a2 += (float)v[q][2] * wv[q];
        a3 += (float)v[q][3] * wv[q];
      }
    }
  }
  f16x4 o;
  o[0] = (_Float16)a0; o[1] = (_Float16)a1;
  o[2] = (_Float16)a2; o[3] = (_Float16)a3;
  *(f16x4*)(out + (size_t)node * OUT_D + 4 * li) = o;
}

// ---------------- tail: relu(agg3) -> Wv -> Wo -> Wc1 -> Wc2 -> Wc3 --------
__global__ __launch_bounds__(256) void k_tail(
    const _Float16* __restrict__ agg3, const float* __restrict__ Wv,
    const float* __restrict__ bv, const float* __restrict__ Wo,
    const float* __restrict__ bo, const float* __restrict__ Wc1,
    const float* __restrict__ bc1, const float* __restrict__ Wc2,
    const float* __restrict__ bc2, const float* __restrict__ Wc3,
    const float* __restrict__ bc3, float* __restrict__ out, int n) {
  __shared__ float sWv[1024], sWo[1024], sWc1[512], sWc2[512];
  __shared__ float sbv[32], sbo[32], sbc2[32], sWc3[32], sbc1[16], sbc3[1];
  int tid = threadIdx.x;
  for (int i = tid; i < 1024; i += 256) { sWv[i] = Wv[i]; sWo[i] = Wo[i]; }
  for (int i = tid; i < 512; i += 256) { sWc1[i] = Wc1[i]; sWc2[i] = Wc2[i]; }
  if (tid < 32) { sbv[tid] = bv[tid]; sbo[tid] = bo[tid];
                  sbc2[tid] = bc2[tid]; sWc3[tid] = Wc3[tid]; }
  if (tid < 16) sbc1[tid] = bc1[tid];
  if (tid == 0) sbc3[0] = bc3[0];
  __syncthreads();
  int node = blockIdx.x * blockDim.x + tid;
  if (node >= n) return;
  float a[32];
  const f16x8* row8 = (const f16x8*)(agg3 + (size_t)node * 32);
#pragma unroll
  for (int q = 0; q < 4; q++) {
    f16x8 t = row8[q];
#pragma unroll
    for (int i = 0; i < 8; i++) {
      float f = (float)t[i];
      a[8 * q + i] = f > 0.0f ? f : 0.0f;
    }
  }
  float v[32];
#pragma unroll
  for (int j = 0; j < 32; j++) v[j] = sbv[j];
  for (int k = 0; k < 32; k++) {
#pragma unroll
    for (int j = 0; j < 32; j++) v[j] += a[k] * sWv[k * 32 + j];
  }
  float o[32];
#pragma unroll
  for (int j = 0; j < 32; j++) o[j] = sbo[j];
  for (int k = 0; k < 32; k++) {
#pragma unroll
    for (int j = 0; j < 32; j++) o[j] += v[k] * sWo[k * 32 + j];
  }
  float c1[16];
#pragma unroll
  for (int j = 0; j < 16; j++) c1[j] = sbc1[j];
  for (int k = 0; k < 32; k++) {
#pragma unroll
    for (int j = 0; j < 16; j++) c1[j] += o[k] * sWc1[k * 16 + j];
  }
#pragma unroll
  for (int j = 0; j < 16; j++) c1[j] = c1[j] > 0.0f ? c1[j] : 0.0f;
  float c2[32];
#pragma unroll
  for (int j = 0; j < 32; j++) c2[j] = sbc2[j];
  for (int k = 0; k < 16; k++) {
#pragma unroll
    for (int j = 0; j < 32; j++) c2[j] += c1[k] * sWc2[k * 32 + j];
  }
  float r = sbc3[0];
#pragma unroll
  for (int k = 0; k < 32; k++) {
    float c = c2[k] > 0.0f ? c2[k] : 0.0f;
    r += c * sWc3[k];
  }
  out[node] = r;
}

// ---------------------------------------------------------------------------
extern "C" void kernel_launch(void* const* d_in, const int* in_sizes, int n_in,
                              void* d_out, int out_size, void* d_ws, size_t ws_size,
                              hipStream_t stream) {
  const float* x   = (const float*)d_in[0];
  const int* ei    = (const int*)d_in[1];
  const float* Wi  = (const float*)d_in[2];
  const float* bi  = (const float*)d_in[3];
  const float* g1  = (const float*)d_in[4];
  const float* b1  = (const float*)d_in[5];
  const float* Wg1 = (const float*)d_in[6];
  const float* bg1 = (const float*)d_in[7];
  const float* Wg2 = (const float*)d_in[8];
  const float* bg2 = (const float*)d_in[9];
  const float* g2  = (const float*)d_in[10];
  const float* b2  = (const float*)d_in[11];
  const float* Wg3 = (const float*)d_in[12];
  const float* bg3 = (const float*)d_in[13];
  // d_in[14..17]: Wq,bq,Wk,bk — mathematically dead (softmax over 1 key == 1)
  const float* Wv  = (const float*)d_in[18];
  const float* bv  = (const float*)d_in[19];
  const float* Wo  = (const float*)d_in[20];
  const float* bo  = (const float*)d_in[21];
  const float* Wc1 = (const float*)d_in[22];
  const float* bc1 = (const float*)d_in[23];
  const float* Wc2 = (const float*)d_in[24];
  const float* bc2 = (const float*)d_in[25];
  const float* Wc3 = (const float*)d_in[26];
  const float* bc3 = (const float*)d_in[27];

  const int n = in_sizes[0] / 164;
  const int e = in_sizes[1] / 2;
  const int* src = ei;
  const int* dst = ei + e;

  // workspace layout (256B aligned)
  char* ws = (char*)d_ws;
  size_t off = 0;
  auto alloc = [&](size_t bytes) {
    char* p = ws + off;
    off += (bytes + 255) & ~(size_t)255;
    return p;
  };
  _Float16* A     = (_Float16*)alloc((size_t)n * 128 * 2);
  _Float16* B     = (_Float16*)alloc((size_t)n * 128 * 2);
  _Float16* C     = (_Float16*)alloc((size_t)n * 128 * 2);
  float* dinv     = (float*)alloc((size_t)n * 4);
  int*   counts   = (int*)alloc((size_t)n * 4);
  int*   offsets  = (int*)alloc((size_t)(n + 1) * 4);
  int*   bsums    = (int*)alloc(256 * 4);
  int2*  csr      = (int2*)alloc((size_t)e * 8);
  _Float16* pWi   = (_Float16*)alloc(3072 * 16);
  _Float16* pWg1  = (_Float16*)alloc(2048 * 16);
  _Float16* pWg2  = (_Float16*)alloc(1024 * 16);
  _Float16* pWg3  = (_Float16*)alloc(256 * 16);
  float* zp       = (float*)alloc(64 * 4);
  (void)ws_size;

  const int BS = 256;
  const int SB = (n + 1023) / 1024;
  const int GB = (n + 63) / 64;   // 64-row gemm blocks (1563)

  // ---- setup ----
  k_setup<<<25 + (n + 255) / 256, 256, 0, stream>>>(
      Wi, Wg1, Wg2, Wg3, pWi, pWg1, pWg2, pWg3, counts, zp, n);

  // ---- CSR build ----
  k_count<<<(e + BS - 1) / BS, BS, 0, stream>>>(dst, counts, e);
  k_scan_part<<<SB, 256, 0, stream>>>(counts, bsums, n);
  k_scan_down<<<SB, 256, 0, stream>>>(counts, bsums, offsets, dinv, n, e, SB);
  k_fill<<<(e + BS - 1) / BS, BS, 0, stream>>>(src, dst, offsets, counts, dinv,
                                               csr, e);

  // ---- fused input + conv1 GEMM: A = h, B = xw1 ----
  k_gemm_in1<<<GB, 256, 0, stream>>>(x, pWi, pWg1, bi, g1, b1, zp, A, B, n);

  // ---- conv1 gather -> C = h1 = relu(agg)+h ----
  k_gather8<128, 0><<<(n + 15) / 16, 256, 0, stream>>>(
      offsets, csr, B, dinv, bg1, A, nullptr, nullptr, C, n);

  // ---- conv2 ----
  k_gemm_f16<128, 64><<<GB, 256, 0, stream>>>(C, pWg2, zp, A, n);
  k_gather8<64, 1><<<(n + 31) / 32, 256, 0, stream>>>(
      offsets, csr, A, dinv, bg2, nullptr, g2, b2, B, n);

  // ---- conv3 ----
  k_gemm_f16<64, 32><<<GB, 256, 0, stream>>>(B, pWg3, zp, A, n);
  k_gather3<<<(n + 31) / 32, 256, 0, stream>>>(
      offsets, csr, A, dinv, bg3, C, n);

  // ---- tail ----
  k_tail<<<(n + BS - 1) / BS, BS, 0, stream>>>(
      C, Wv, bv, Wo, bo, Wc1, bc1, Wc2, bc2, Wc3, bc3, (float*)d_out, n);
}